// Round 4
// baseline (199.972 us; speedup 1.0000x reference)
//
#include <hip/hip_runtime.h>

#define N 4096
#define GRID 1024

// XOR-swizzled float2 slot: bijective on [0,4096); distributes banks for all
// four patterns (t*16+i, b1*256+j*16+c1 rw, j*256+t) within each 16-lane group.
__device__ __forceinline__ int swz(int e) { return e ^ ((e >> 4) & 15); }

__global__ __launch_bounds__(256, 4) void butterfly4_kernel(
    const float* __restrict__ x,
    const float* __restrict__ w0, const float* __restrict__ w1, const float* __restrict__ w2,
    const float* __restrict__ l0, const float* __restrict__ l1, const float* __restrict__ l2,
    float* __restrict__ out, int pairs)
{
    __shared__ float2 lds[N];                 // 32 KiB exactly
    const int t = threadIdx.x;
    const int b1 = t >> 4, c1 = t & 15;

    // loop-invariant weight columns: loaded ONCE per block
    float w1c[16], w0c[16];
    #pragma unroll
    for (int j = 0; j < 16; ++j) w1c[j] = w1[j*16 + c1];
    #pragma unroll
    for (int j = 0; j < 16; ++j) w0c[j] = w0[j*256 + t];

    // prologue: load first pair
    float vA[16], vB[16];
    {
        const float4* qA = (const float4*)(x + (size_t)blockIdx.x*2*N + t*16);
        const float4* qB = (const float4*)(x + ((size_t)blockIdx.x*2+1)*N + t*16);
        #pragma unroll
        for (int q = 0; q < 4; ++q) {
            float4 f = qA[q];
            vA[q*4+0]=f.x; vA[q*4+1]=f.y; vA[q*4+2]=f.z; vA[q*4+3]=f.w;
        }
        #pragma unroll
        for (int q = 0; q < 4; ++q) {
            float4 f = qB[q];
            vB[q*4+0]=f.x; vB[q*4+1]=f.y; vB[q*4+2]=f.z; vB[q*4+3]=f.w;
        }
    }

    for (int p = blockIdx.x; p < pairs; p += GRID) {
        const float* __restrict__ xA = x + (size_t)p*2*N;
        const float* __restrict__ xB = xA + N;
        float* __restrict__ oA = out + (size_t)p*2*N;
        float* __restrict__ oB = oA + N;

        // ---- level 2 (thread-local, residual = x) -> T1 write (wave-private) ----
        float xwA[16], xwB[16];
        #pragma unroll
        for (int j = 0; j < 16; ++j) { float s = w2[j]; xwA[j]=s*vA[j]; xwB[j]=s*vB[j]; }
        #pragma unroll
        for (int i = 0; i < 16; ++i) {
            float a = vA[i], b = vB[i];
            #pragma unroll
            for (int j = 0; j < 16; ++j) {
                float s = l2[i*16+j];
                a = fmaf(s, xwA[j], a);
                b = fmaf(s, xwB[j], b);
            }
            lds[swz(t*16 + i)] = make_float2(a, b);
        }

        // ---- level 1 (intra-wave exchange; no barrier needed) ----
        float2 y1[16];
        #pragma unroll
        for (int j = 0; j < 16; ++j) {
            float2 q = lds[swz(b1*256 + j*16 + c1)];
            y1[j].x = w1c[j]*q.x; y1[j].y = w1c[j]*q.y;
        }
        #pragma unroll
        for (int i = 0; i < 16; ++i) {
            float a = 0.f, b = 0.f;
            #pragma unroll
            for (int j = 0; j < 16; ++j) {
                float s = l1[i*16+j];
                a = fmaf(s, y1[j].x, a);
                b = fmaf(s, y1[j].y, b);
            }
            lds[swz(b1*256 + i*16 + c1)] = make_float2(a, b);   // WAR on own slots
        }

        __syncthreads();                       // T2 write -> T2 read (cross-wave)

        float2 y0[16];
        #pragma unroll
        for (int j = 0; j < 16; ++j) {
            float2 q = lds[swz(j*256 + t)];
            y0[j].x = w0c[j]*q.x; y0[j].y = w0c[j]*q.y;
        }

        __syncthreads();                       // T2 reads done -> LDS free for next iter

        // prefetch next pair AFTER the last barrier of this iteration: loads stay
        // in flight through L0 compute + stores + next iteration's level-2 FMAs
        const bool more = (p + GRID) < pairs;
        float pA[16], pB[16];
        if (more) {
            const float4* nA = (const float4*)(xA + (size_t)GRID*2*N + t*16);
            const float4* nB = (const float4*)(xB + (size_t)GRID*2*N + t*16);
            #pragma unroll
            for (int q = 0; q < 4; ++q) {
                float4 f = nA[q];
                pA[q*4+0]=f.x; pA[q*4+1]=f.y; pA[q*4+2]=f.z; pA[q*4+3]=f.w;
            }
            #pragma unroll
            for (int q = 0; q < 4; ++q) {
                float4 f = nB[q];
                pB[q*4+0]=f.x; pB[q*4+1]=f.y; pB[q*4+2]=f.z; pB[q*4+3]=f.w;
            }
        }

        // ---- level 0 (residual re-read of x: L2-hot) + coalesced stores ----
        #pragma unroll
        for (int i = 0; i < 16; ++i) {
            float a = xA[i*256 + t];
            float b = xB[i*256 + t];
            #pragma unroll
            for (int j = 0; j < 16; ++j) {
                float s = l0[i*16+j];
                a = fmaf(s, y0[j].x, a);
                b = fmaf(s, y0[j].y, b);
            }
            oA[i*256 + t] = a;
            oB[i*256 + t] = b;
        }

        if (more) {
            #pragma unroll
            for (int k = 0; k < 16; ++k) { vA[k] = pA[k]; vB[k] = pB[k]; }
        }
    }
}

extern "C" void kernel_launch(void* const* d_in, const int* in_sizes, int n_in,
                              void* d_out, int out_size, void* d_ws, size_t ws_size,
                              hipStream_t stream) {
    const float* x  = (const float*)d_in[0];
    const float* w0 = (const float*)d_in[1];
    const float* w1 = (const float*)d_in[2];
    const float* w2 = (const float*)d_in[3];
    const float* l0 = (const float*)d_in[4];
    const float* l1 = (const float*)d_in[5];
    const float* l2 = (const float*)d_in[6];
    float* out = (float*)d_out;
    const int pairs = (in_sizes[0] / N) / 2;
    butterfly4_kernel<<<GRID, 256, 0, stream>>>(x, w0, w1, w2, l0, l1, l2, out, pairs);
}

// Round 5
// 68.927 us; speedup vs baseline: 2.9012x; 2.9012x over previous
//
#include <hip/hip_runtime.h>

#define N 4096

// XOR swizzle on float2 slot index: s = e ^ ((e>>4)&15). Bijective per 16-slot
// block; verified conflict-free per 16-lane group for all four access patterns
// (t*16+i, b1*256+j*16+c1 r/w, j*256+t). LDS shrinks to exactly 32 KiB -> 5 blocks/CU.
__device__ __forceinline__ int swz(int e) { return e ^ ((e >> 4) & 15); }

__global__ __launch_bounds__(256, 6) void butterfly5_kernel(
    const float* __restrict__ x,
    const float* __restrict__ w0, const float* __restrict__ w1, const float* __restrict__ w2,
    const float* __restrict__ l0, const float* __restrict__ l1, const float* __restrict__ l2,
    float* __restrict__ out)
{
    __shared__ float2 lds[N];                 // 32768 B exactly
    const int t = threadIdx.x;
    const int b1 = t >> 4, c1 = t & 15;
    const size_t row0 = (size_t)blockIdx.x * 2;
    const float* __restrict__ xA = x + row0 * N;
    const float* __restrict__ xB = xA + N;
    float* __restrict__ oA = out + row0 * N;
    float* __restrict__ oB = oA + N;

    // ---- load 16 contiguous elements for each of the two rows ----
    float vA[16], vB[16];
    {
        const float4* qA = (const float4*)(xA + t * 16);
        const float4* qB = (const float4*)(xB + t * 16);
        #pragma unroll
        for (int q = 0; q < 4; ++q) {
            float4 f = qA[q];
            vA[q*4+0]=f.x; vA[q*4+1]=f.y; vA[q*4+2]=f.z; vA[q*4+3]=f.w;
        }
        #pragma unroll
        for (int q = 0; q < 4; ++q) {
            float4 f = qB[q];
            vB[q*4+0]=f.x; vB[q*4+1]=f.y; vB[q*4+2]=f.z; vB[q*4+3]=f.w;
        }
    }

    // ---- level 2 (thread-local 16x16 matvec, residual = x) ----
    float xwA[16], xwB[16];
    #pragma unroll
    for (int j = 0; j < 16; ++j) {
        float s = w2[j];                 // uniform -> SGPR
        xwA[j] = s * vA[j];
        xwB[j] = s * vB[j];
    }
    #pragma unroll
    for (int i = 0; i < 16; ++i) {
        float a = vA[i], b = vB[i];
        #pragma unroll
        for (int j = 0; j < 16; ++j) {
            float s = l2[i*16 + j];      // uniform -> SGPR
            a = fmaf(s, xwA[j], a);
            b = fmaf(s, xwB[j], b);
        }
        lds[swz(t*16 + i)] = make_float2(a, b);   // wave-private region
    }

    float w1c[16];
    #pragma unroll
    for (int j = 0; j < 16; ++j) w1c[j] = w1[j*16 + c1];

    // ---- level 1 (intra-wave exchange, no barrier, no residual) ----
    float2 y1[16];
    #pragma unroll
    for (int j = 0; j < 16; ++j) {
        float2 p = lds[swz(b1*256 + j*16 + c1)];
        y1[j].x = w1c[j] * p.x;
        y1[j].y = w1c[j] * p.y;
    }
    float2 r1[16];
    #pragma unroll
    for (int i = 0; i < 16; ++i) {
        float a = 0.f, b = 0.f;
        #pragma unroll
        for (int j = 0; j < 16; ++j) {
            float s = l1[i*16 + j];
            a = fmaf(s, y1[j].x, a);
            b = fmaf(s, y1[j].y, b);
        }
        r1[i] = make_float2(a, b);
    }
    #pragma unroll
    for (int i = 0; i < 16; ++i)
        lds[swz(b1*256 + i*16 + c1)] = r1[i];     // WAR on own wave's slots

    // w0 column + residual x: issued pre-barrier (overlap with L1 compute;
    // drained complete at the barrier — latency paid under compute)
    float w0c[16], xrA[16], xrB[16];
    #pragma unroll
    for (int j = 0; j < 16; ++j) w0c[j] = w0[j*256 + t];
    #pragma unroll
    for (int i = 0; i < 16; ++i) { xrA[i] = xA[i*256 + t]; xrB[i] = xB[i*256 + t]; }

    __syncthreads();   // the single cross-wave handoff

    // ---- level 0 (stride-256 mix, residual = original x), NT stores ----
    float2 y0[16];
    #pragma unroll
    for (int j = 0; j < 16; ++j) {
        float2 p = lds[swz(j*256 + t)];
        y0[j].x = w0c[j] * p.x;
        y0[j].y = w0c[j] * p.y;
    }
    #pragma unroll
    for (int i = 0; i < 16; ++i) {
        float a = xrA[i], b = xrB[i];
        #pragma unroll
        for (int j = 0; j < 16; ++j) {
            float s = l0[i*16 + j];
            a = fmaf(s, y0[j].x, a);
            b = fmaf(s, y0[j].y, b);
        }
        __builtin_nontemporal_store(a, &oA[i*256 + t]);  // out never re-read:
        __builtin_nontemporal_store(b, &oB[i*256 + t]);  // keep L2 clean for x
    }
}

extern "C" void kernel_launch(void* const* d_in, const int* in_sizes, int n_in,
                              void* d_out, int out_size, void* d_ws, size_t ws_size,
                              hipStream_t stream) {
    const float* x  = (const float*)d_in[0];
    const float* w0 = (const float*)d_in[1];
    const float* w1 = (const float*)d_in[2];
    const float* w2 = (const float*)d_in[3];
    const float* l0 = (const float*)d_in[4];
    const float* l1 = (const float*)d_in[5];
    const float* l2 = (const float*)d_in[6];
    float* out = (float*)d_out;
    const int rows = in_sizes[0] / N;
    butterfly5_kernel<<<rows / 2, 256, 0, stream>>>(x, w0, w1, w2, l0, l1, l2, out);
}